// Round 1
// baseline (113.512 us; speedup 1.0000x reference)
//
#include <hip/hip_runtime.h>
#include <hip/hip_bf16.h>

// NNConv collapsed algebraically:
//   out = x @ root + bias + mean_broadcast
//   mean[n] = (1/(64*cnt[n])) * sum_{e: col[e]==n} ( ea[e,:] . g[row[e],:] + h[row[e]] )
//   g[n,d]  = sum_c Wsum[d,c] * x[n,c],  Wsum[d,c] = sum_o W_nn[d, c*64+o]
//   h[n]    = sum_c bsum[c]  * x[n,c],  bsum[c]   = sum_o b_nn[c*64+o]

#define CC 64
#define DE 16

// ---- Kernel A: Wsum (16x64) and bsum (64) ----------------------------------
__global__ __launch_bounds__(1024) void k_wsum(const float* __restrict__ W,
                                               const float* __restrict__ b,
                                               float* __restrict__ wsum,
                                               float* __restrict__ bsum) {
    int p = threadIdx.x;            // 0..1023 ; p = d*64 + c
    int d = p >> 6, c = p & 63;
    const float4* w4 = (const float4*)(W + (size_t)d * (CC * CC) + c * CC);
    float s = 0.f;
#pragma unroll
    for (int i = 0; i < 16; ++i) { float4 v = w4[i]; s += v.x + v.y + v.z + v.w; }
    wsum[p] = s;
    if (p < CC) {
        const float4* b4 = (const float4*)(b + p * CC);
        float sb = 0.f;
#pragma unroll
        for (int i = 0; i < 16; ++i) { float4 v = b4[i]; sb += v.x + v.y + v.z + v.w; }
        bsum[p] = sb;
    }
}

// ---- Kernel B: per-node g (N x 16) and h (N) -------------------------------
__global__ __launch_bounds__(256) void k_node(const float* __restrict__ x,
                                              const float* __restrict__ wsum_bsum, // 1024 + 64 floats
                                              float* __restrict__ g,
                                              float* __restrict__ h,
                                              int N) {
    __shared__ float ws[1024 + 64];
    int tid = threadIdx.x;
#pragma unroll
    for (int i = 0; i < 4; ++i) ws[tid + i * 256] = wsum_bsum[tid + i * 256];
    if (tid < 64) ws[1024 + tid] = wsum_bsum[1024 + tid];
    __syncthreads();

    int n = blockIdx.x * 256 + tid;
    if (n >= N) return;

    const float4* x4 = (const float4*)(x + (size_t)n * CC);
    const float4* ws4 = (const float4*)ws;          // ws4[d*16 + c4]
    const float4* bs4 = (const float4*)(ws + 1024); // bs4[c4]

    float acc[DE];
#pragma unroll
    for (int d = 0; d < DE; ++d) acc[d] = 0.f;
    float hh = 0.f;

#pragma unroll
    for (int c4 = 0; c4 < 16; ++c4) {
        float4 xv = x4[c4];
        float4 bv = bs4[c4];                         // LDS broadcast (uniform addr)
        hh += bv.x * xv.x + bv.y * xv.y + bv.z * xv.z + bv.w * xv.w;
#pragma unroll
        for (int d = 0; d < DE; ++d) {
            float4 wv = ws4[d * 16 + c4];            // LDS b128 broadcast
            acc[d] += wv.x * xv.x + wv.y * xv.y + wv.z * xv.z + wv.w * xv.w;
        }
    }
    float4* g4 = (float4*)(g + (size_t)n * DE);
    g4[0] = make_float4(acc[0], acc[1], acc[2], acc[3]);
    g4[1] = make_float4(acc[4], acc[5], acc[6], acc[7]);
    g4[2] = make_float4(acc[8], acc[9], acc[10], acc[11]);
    g4[3] = make_float4(acc[12], acc[13], acc[14], acc[15]);
    h[n] = hh;
}

// ---- Kernel C: per-edge scalar + scatter -----------------------------------
__global__ __launch_bounds__(256) void k_edge(const int* __restrict__ ei,
                                              const float* __restrict__ ea,
                                              const float* __restrict__ g,
                                              const float* __restrict__ h,
                                              float* __restrict__ seg,
                                              float* __restrict__ cnt,
                                              int E) {
    int e = blockIdx.x * 256 + threadIdx.x;
    if (e >= E) return;
    int r = ei[e];
    int cn = ei[E + e];
    const float4* a4 = (const float4*)(ea + (size_t)e * DE);
    const float4* g4 = (const float4*)(g + (size_t)r * DE);
    float4 a0 = a4[0], a1 = a4[1], a2 = a4[2], a3 = a4[3];
    float4 g0 = g4[0], g1 = g4[1], g2 = g4[2], g3 = g4[3];
    float s = h[r]
        + a0.x * g0.x + a0.y * g0.y + a0.z * g0.z + a0.w * g0.w
        + a1.x * g1.x + a1.y * g1.y + a1.z * g1.z + a1.w * g1.w
        + a2.x * g2.x + a2.y * g2.y + a2.z * g2.z + a2.w * g2.w
        + a3.x * g3.x + a3.y * g3.y + a3.z * g3.z + a3.w * g3.w;
    atomicAdd(seg + cn, s);
    atomicAdd(cnt + cn, 1.0f);
}

// ---- Kernel D: out = x @ root + bias + mean --------------------------------
__global__ __launch_bounds__(256) void k_final(const float* __restrict__ x,
                                               const float* __restrict__ root,
                                               const float* __restrict__ bias,
                                               const float* __restrict__ seg,
                                               const float* __restrict__ cnt,
                                               float* __restrict__ out,
                                               int N) {
    __shared__ float rt[CC * CC];   // 16 KB
    __shared__ float xs[4 * CC];
    __shared__ float bi[CC];
    __shared__ float mn[4];
    int tid = threadIdx.x;
    int n0 = blockIdx.x * 4;

#pragma unroll
    for (int i = 0; i < 16; ++i) rt[tid + i * 256] = root[tid + i * 256];
    if (n0 * CC + tid < N * CC) xs[tid] = x[(size_t)n0 * CC + tid];
    if (tid < CC) bi[tid] = bias[tid];
    if (tid < 4 && n0 + tid < N) {
        float c = cnt[n0 + tid];
        mn[tid] = c > 0.f ? seg[n0 + tid] / (c * (float)CC) : 0.f;
    }
    __syncthreads();

    int nl = tid >> 6, c = tid & 63;
    int n = n0 + nl;
    if (n >= N) return;
    float acc = bi[c] + mn[nl];
#pragma unroll
    for (int k = 0; k < CC; ++k) acc += xs[nl * CC + k] * rt[k * CC + c];
    out[(size_t)n * CC + c] = acc;
}

extern "C" void kernel_launch(void* const* d_in, const int* in_sizes, int n_in,
                              void* d_out, int out_size, void* d_ws, size_t ws_size,
                              hipStream_t stream) {
    const float* x    = (const float*)d_in[0];
    const int*   ei   = (const int*)  d_in[1];
    const float* ea   = (const float*)d_in[2];
    const float* W    = (const float*)d_in[3];
    const float* b    = (const float*)d_in[4];
    const float* root = (const float*)d_in[5];
    const float* bias = (const float*)d_in[6];
    float* out = (float*)d_out;
    float* ws  = (float*)d_ws;

    const int N = in_sizes[0] / CC;   // 10000
    const int E = in_sizes[1] / 2;    // 100000

    // workspace layout (floats):
    float* wsum = ws;                 // [0, 1024)   Wsum then bsum contiguous
    float* h    = ws + 1088;          // [1088, 1088+N)
    float* seg  = ws + 1088 + N;      // zeroed
    float* cnt  = ws + 1088 + 2 * N;  // zeroed
    float* g    = ws + 1088 + 3 * N;  // N*16 floats, 16B-aligned (31088*4 % 16 == 0)

    hipMemsetAsync(seg, 0, (size_t)2 * N * sizeof(float), stream);

    k_wsum<<<1, 1024, 0, stream>>>(W, b, wsum, wsum + 1024);
    k_node<<<(N + 255) / 256, 256, 0, stream>>>(x, wsum, g, h, N);
    k_edge<<<(E + 255) / 256, 256, 0, stream>>>(ei, ea, g, h, seg, cnt, E);
    k_final<<<(N + 3) / 4, 256, 0, stream>>>(x, root, bias, seg, cnt, out, N);
}